// Round 19
// baseline (1759.699 us; speedup 1.0000x reference)
//
#include <hip/hip_runtime.h>
#include <hip/hip_bf16.h>
#include <math.h>

static constexpr int NLAT = 128, NLON = 256, MM = 128;
static constexpr int EMB = 256, INCH = 36, OUTCH = 6, HID = 512, NLAYERS = 4;
static constexpr int YN = 32768;
static constexpr long RB = 4194304;

using bf16x8 = __attribute__((ext_vector_type(8))) __bf16;
using f32x4  = __attribute__((ext_vector_type(4))) float;

static constexpr int BM = 128, BN = 128, BK = 32, LDP = 40;

__device__ __forceinline__ void cvt_hl(float v, __bf16& h, __bf16& l)
{
    h = (__bf16)v;
    l = (__bf16)(v - (float)h);
}
__device__ __forceinline__ void pack_hi_lo(const float* v, bf16x8& h0, bf16x8& h1,
                                           bf16x8& l0, bf16x8& l1)
{
    #pragma unroll
    for (int e = 0; e < 8; ++e) {
        const __bf16 h = (__bf16)v[e];
        h0[e] = h; l0[e] = (__bf16)(v[e] - (float)h);
        const __bf16 g = (__bf16)v[e + 8];
        h1[e] = g; l1[e] = (__bf16)(v[e + 8] - (float)g);
    }
}

#define GLOAD16(g, l) __builtin_amdgcn_global_load_lds( \
    (const __attribute__((address_space(1))) void*)(g), \
    (__attribute__((address_space(3))) void*)(l), 16, 0, 0)

// ======================= f32-input split NT GEMM (3-term, proven) =======================
__global__ __launch_bounds__(256)
void gemm_nt(const float* __restrict__ A, const float* __restrict__ B,
             float* __restrict__ C, int M, int N, int K,
             int lda, int ldb, int ldc,
             const float* __restrict__ bias, int biasCol,
             const float* __restrict__ addsrc,
             float alpha, int accum, int relu)
{
    __shared__ __bf16 Ah[BM][LDP], Al[BM][LDP], Bh[BN][LDP], Bl[BN][LDP];

    const int m0 = blockIdx.y * BM, n0 = blockIdx.x * BN;
    const int tid = threadIdx.x, lane = tid & 63, wave = tid >> 6;
    const int wr = wave >> 1, wc = wave & 1;
    const int fr = lane & 15, fkb = lane >> 4;
    const int sr = tid >> 1, sh = (tid & 1) << 4;

    f32x4 acc[4][4];
    #pragma unroll
    for (int i = 0; i < 4; ++i)
        #pragma unroll
        for (int j = 0; j < 4; ++j) acc[i][j] = (f32x4)0.f;

    const int ga = m0 + sr, gb = n0 + sr;
    const float* Arow = A + (long)ga * lda + sh;
    const float* Brow = B + (long)gb * ldb + sh;

    bf16x8 sAh0, sAh1, sAl0, sAl1, sBh0, sBh1, sBl0, sBl1;

    auto loadA = [&](int k0) {
        float v[16];
        if (ga < M && (k0 + sh + 16) <= K) {
            #pragma unroll
            for (int q = 0; q < 4; ++q) {
                const float4 f = *(const float4*)(Arow + k0 + q * 4);
                v[q*4+0]=f.x; v[q*4+1]=f.y; v[q*4+2]=f.z; v[q*4+3]=f.w;
            }
        } else {
            #pragma unroll
            for (int e = 0; e < 16; ++e)
                v[e] = (ga < M && (k0 + sh + e) < K) ? Arow[k0 + e] : 0.f;
        }
        pack_hi_lo(v, sAh0, sAh1, sAl0, sAl1);
    };
    auto loadB = [&](int k0) {
        float v[16];
        if (gb < N && (k0 + sh + 16) <= K) {
            #pragma unroll
            for (int q = 0; q < 4; ++q) {
                const float4 f = *(const float4*)(Brow + k0 + q * 4);
                v[q*4+0]=f.x; v[q*4+1]=f.y; v[q*4+2]=f.z; v[q*4+3]=f.w;
            }
        } else {
            #pragma unroll
            for (int e = 0; e < 16; ++e)
                v[e] = (gb < N && (k0 + sh + e) < K) ? Brow[k0 + e] : 0.f;
        }
        pack_hi_lo(v, sBh0, sBh1, sBl0, sBl1);
    };

    loadA(0); loadB(0);

    for (int k0 = 0; k0 < K; k0 += BK) {
        *(bf16x8*)&Ah[sr][sh]     = sAh0;  *(bf16x8*)&Ah[sr][sh + 8] = sAh1;
        *(bf16x8*)&Al[sr][sh]     = sAl0;  *(bf16x8*)&Al[sr][sh + 8] = sAl1;
        *(bf16x8*)&Bh[sr][sh]     = sBh0;  *(bf16x8*)&Bh[sr][sh + 8] = sBh1;
        *(bf16x8*)&Bl[sr][sh]     = sBl0;  *(bf16x8*)&Bl[sr][sh + 8] = sBl1;
        __syncthreads();

        if (k0 + BK < K) { loadA(k0 + BK); loadB(k0 + BK); }

        bf16x8 fah[4], fal[4], fbh[4], fbl[4];
        #pragma unroll
        for (int i = 0; i < 4; ++i) {
            const int r = wr * 64 + i * 16 + fr;
            fah[i] = *(const bf16x8*)&Ah[r][fkb * 8];
            fal[i] = *(const bf16x8*)&Al[r][fkb * 8];
        }
        #pragma unroll
        for (int j = 0; j < 4; ++j) {
            const int c = wc * 64 + j * 16 + fr;
            fbh[j] = *(const bf16x8*)&Bh[c][fkb * 8];
            fbl[j] = *(const bf16x8*)&Bl[c][fkb * 8];
        }
        #pragma unroll
        for (int i = 0; i < 4; ++i)
            #pragma unroll
            for (int j = 0; j < 4; ++j) {
                acc[i][j] = __builtin_amdgcn_mfma_f32_16x16x32_bf16(fah[i], fbh[j], acc[i][j], 0, 0, 0);
                acc[i][j] = __builtin_amdgcn_mfma_f32_16x16x32_bf16(fah[i], fbl[j], acc[i][j], 0, 0, 0);
                acc[i][j] = __builtin_amdgcn_mfma_f32_16x16x32_bf16(fal[i], fbh[j], acc[i][j], 0, 0, 0);
            }
        __syncthreads();
    }

    const int crow0 = (lane >> 4) * 4;
    #pragma unroll
    for (int i = 0; i < 4; ++i)
        #pragma unroll
        for (int j = 0; j < 4; ++j)
            #pragma unroll
            for (int r = 0; r < 4; ++r) {
                const int gm = m0 + wr * 64 + i * 16 + crow0 + r;
                const int gn = n0 + wc * 64 + j * 16 + fr;
                if (gm < M && gn < N) {
                    const long idx = (long)gm * ldc + gn;
                    float v = acc[i][j][r] * alpha;
                    if (accum)  v += C[idx];
                    if (bias)   v += bias[biasCol ? gn : gm];
                    if (addsrc) v += addsrc[idx];
                    if (relu)   v = fmaxf(v, 0.f);
                    C[idx] = v;
                }
            }
}

// ======================= all-bf16 NT GEMM, 2-segment, gload_lds + dbuf + 1 barrier ===========
// C = A1·B1^T [+ A2·B2^T] (+bias[col]) (+addsrc f32) (relu) -> f32 or bf16 out.
// Requires: M,N row-padded data (no masks in staging), K segments multiples of 64.
__global__ __launch_bounds__(256)
void gemm_bb(const __bf16* __restrict__ A1, const __bf16* __restrict__ B1,
             int K1, int lda1, int ldb1,
             const __bf16* __restrict__ A2, const __bf16* __restrict__ B2,
             int K2, int lda2, int ldb2,
             float* __restrict__ Cf, __bf16* __restrict__ Cb,
             int M, int N, int ldc,
             const float* __restrict__ bias, const float* __restrict__ addsrc,
             int relu)
{
    __shared__ __bf16 lds[2][2][128 * 64];   // [buf][op][row*64+k], 64 KB

    const int m0 = blockIdx.y * BM, n0 = blockIdx.x * BN;
    const int tid = threadIdx.x, lane = tid & 63, wave = tid >> 6;
    const int wr = wave >> 1, wc = wave & 1;
    const int fr = lane & 15, fkb = lane >> 4;

    // staging role: wave>>1 selects op (0:A,1:B); wave&1 selects 64-row half
    const int sop = wave >> 1;
    const int rl0 = (wave & 1) * 64 + (lane >> 3);            // row_local for iter 0, +8/iter
    const long gch = (long)(((lane & 7) ^ (lane >> 3)) << 4); // swizzled global chunk (bytes)

    const int s1 = K1 >> 6;
    const int s2 = A2 ? (K2 >> 6) : 0;
    const int ns = s1 + s2;

    auto stageStep = [&](int buf, int t) {
        const __bf16* base;
        int ld, k0;
        if (t < s1) { base = sop ? B1 : A1; ld = sop ? ldb1 : lda1; k0 = t << 6; }
        else        { base = sop ? B2 : A2; ld = sop ? ldb2 : lda2; k0 = (t - s1) << 6; }
        const int row0 = sop ? n0 : m0;
        const char* g = (const char*)base + ((long)(row0 + rl0) * ld + k0) * 2 + gch;
        char* p = (char*)&lds[buf][sop][0] + (wave & 1) * 8192 + lane * 16;
        const long gstep = (long)8 * ld * 2;
        #pragma unroll
        for (int i = 0; i < 8; ++i) {
            GLOAD16(g, p);
            g += gstep;
            p += 1024;
        }
    };

    f32x4 acc[4][4];
    #pragma unroll
    for (int i = 0; i < 4; ++i)
        #pragma unroll
        for (int j = 0; j < 4; ++j) acc[i][j] = (f32x4)0.f;

    stageStep(0, 0);
    __syncthreads();

    int cur = 0;
    for (int t = 0; t < ns; ++t) {
        if (t + 1 < ns) stageStep(cur ^ 1, t + 1);   // loads fly under this step's MFMA

        const char* Alds = (const char*)&lds[cur][0][0];
        const char* Blds = (const char*)&lds[cur][1][0];
        bf16x8 fa[4][2], fb[4][2];
        #pragma unroll
        for (int i = 0; i < 4; ++i) {
            const int r = wr * 64 + i * 16 + fr;
            const char* rp = Alds + r * 128;
            fa[i][0] = *(const bf16x8*)(rp + (((fkb)     ^ (r & 7)) << 4));
            fa[i][1] = *(const bf16x8*)(rp + (((4 | fkb) ^ (r & 7)) << 4));
        }
        #pragma unroll
        for (int j = 0; j < 4; ++j) {
            const int c = wc * 64 + j * 16 + fr;
            const char* rp = Blds + c * 128;
            fb[j][0] = *(const bf16x8*)(rp + (((fkb)     ^ (c & 7)) << 4));
            fb[j][1] = *(const bf16x8*)(rp + (((4 | fkb) ^ (c & 7)) << 4));
        }
        #pragma unroll
        for (int i = 0; i < 4; ++i)
            #pragma unroll
            for (int j = 0; j < 4; ++j) {
                acc[i][j] = __builtin_amdgcn_mfma_f32_16x16x32_bf16(fa[i][0], fb[j][0], acc[i][j], 0, 0, 0);
                acc[i][j] = __builtin_amdgcn_mfma_f32_16x16x32_bf16(fa[i][1], fb[j][1], acc[i][j], 0, 0, 0);
            }
        __syncthreads();   // drains next-step stage; guards buf reuse (single barrier/step)
        cur ^= 1;
    }

    const int crow0 = (lane >> 4) * 4;
    #pragma unroll
    for (int i = 0; i < 4; ++i)
        #pragma unroll
        for (int j = 0; j < 4; ++j)
            #pragma unroll
            for (int r = 0; r < 4; ++r) {
                const int gm = m0 + wr * 64 + i * 16 + crow0 + r;
                const int gn = n0 + wc * 64 + j * 16 + fr;
                if (gm < M && gn < N) {
                    const long idx = (long)gm * ldc + gn;
                    float v = acc[i][j][r];
                    if (bias)   v += bias[gn];
                    if (addsrc) v += addsrc[idx];
                    if (relu)   v = fmaxf(v, 0.f);
                    if (Cf) Cf[idx] = v;
                    if (Cb) Cb[idx] = (__bf16)v;
                }
            }
}

// ======================= bf16 spectral NT GEMM =======================
__global__ __launch_bounds__(256)
void gemm_sp(const __bf16* __restrict__ Ah, const __bf16* __restrict__ Al,
             const __bf16* __restrict__ Bh, const __bf16* __restrict__ Bl,
             int M, int N, int K, int lda, int ldb, int ldc,
             long sAz, long sBz, unsigned zmaskB, long sCz,
             float* __restrict__ outF, __bf16* __restrict__ outB,
             float alpha, int kfromz)
{
    __shared__ __bf16 L0[BM * LDP], L1[BN * LDP], L2[BM * LDP];

    const int z = blockIdx.z;
    const long aOff = (long)z * sAz, bOff = (long)(z & zmaskB) * sBz, cOff = (long)z * sCz;
    const int m0 = blockIdx.y * BM, n0 = blockIdx.x * BN;
    const int tid = threadIdx.x, lane = tid & 63, wave = tid >> 6;
    const int wr = wave >> 1, wc = wave & 1, fr = lane & 15, fkb = lane >> 4;
    const int row = tid >> 1, half = (tid & 1) << 4;
    const int kst = kfromz ? (((z & 127) >> 5) << 5) : 0;
    const bool asp = (Al != nullptr), bsp = (Bl != nullptr);

    const __bf16* Ar = Ah + aOff + (long)(m0 + row) * lda + half;
    const __bf16* Br = Bh + bOff + (long)(n0 + row) * ldb + half;
    const __bf16* Xr = asp ? (Al + aOff + (long)(m0 + row) * lda + half)
                     : (bsp ? (Bl + bOff + (long)(n0 + row) * ldb + half) : nullptr);

    f32x4 acc[4][4];
    #pragma unroll
    for (int i = 0; i < 4; ++i)
        #pragma unroll
        for (int j = 0; j < 4; ++j) acc[i][j] = (f32x4)0.f;

    bf16x8 rA0, rA1, rB0, rB1, rX0, rX1;
    auto load = [&](int k0) {
        rA0 = *(const bf16x8*)(Ar + k0); rA1 = *(const bf16x8*)(Ar + k0 + 8);
        rB0 = *(const bf16x8*)(Br + k0); rB1 = *(const bf16x8*)(Br + k0 + 8);
        if (Xr) { rX0 = *(const bf16x8*)(Xr + k0); rX1 = *(const bf16x8*)(Xr + k0 + 8); }
    };
    load(kst);

    for (int k0 = kst; k0 < K; k0 += BK) {
        *(bf16x8*)&L0[row * LDP + half] = rA0; *(bf16x8*)&L0[row * LDP + half + 8] = rA1;
        *(bf16x8*)&L1[row * LDP + half] = rB0; *(bf16x8*)&L1[row * LDP + half + 8] = rB1;
        if (Xr) { *(bf16x8*)&L2[row * LDP + half] = rX0; *(bf16x8*)&L2[row * LDP + half + 8] = rX1; }
        __syncthreads();
        if (k0 + BK < K) load(k0 + BK);

        bf16x8 fa[4], fb[4], fx[4];
        #pragma unroll
        for (int i = 0; i < 4; ++i)
            fa[i] = *(const bf16x8*)&L0[(wr * 64 + i * 16 + fr) * LDP + fkb * 8];
        #pragma unroll
        for (int j = 0; j < 4; ++j)
            fb[j] = *(const bf16x8*)&L1[(wc * 64 + j * 16 + fr) * LDP + fkb * 8];
        if (asp) {
            #pragma unroll
            for (int i = 0; i < 4; ++i)
                fx[i] = *(const bf16x8*)&L2[(wr * 64 + i * 16 + fr) * LDP + fkb * 8];
        } else if (bsp) {
            #pragma unroll
            for (int j = 0; j < 4; ++j)
                fx[j] = *(const bf16x8*)&L2[(wc * 64 + j * 16 + fr) * LDP + fkb * 8];
        }
        #pragma unroll
        for (int i = 0; i < 4; ++i)
            #pragma unroll
            for (int j = 0; j < 4; ++j) {
                acc[i][j] = __builtin_amdgcn_mfma_f32_16x16x32_bf16(fa[i], fb[j], acc[i][j], 0, 0, 0);
                if (asp) acc[i][j] = __builtin_amdgcn_mfma_f32_16x16x32_bf16(fx[i], fb[j], acc[i][j], 0, 0, 0);
                else if (bsp) acc[i][j] = __builtin_amdgcn_mfma_f32_16x16x32_bf16(fa[i], fx[j], acc[i][j], 0, 0, 0);
            }
        __syncthreads();
    }

    const int crow0 = (lane >> 4) * 4;
    #pragma unroll
    for (int i = 0; i < 4; ++i)
        #pragma unroll
        for (int j = 0; j < 4; ++j)
            #pragma unroll
            for (int r = 0; r < 4; ++r) {
                const int gm = m0 + wr * 64 + i * 16 + crow0 + r;
                const int gn = n0 + wc * 64 + j * 16 + fr;
                const long idx = cOff + (long)gm * ldc + gn;
                const float v = acc[i][j][r] * alpha;
                if (outF) outF[idx] = v;
                if (outB) outB[idx] = (__bf16)v;
            }
}

// ======================= fused dual spec GEMM =======================
__global__ __launch_bounds__(256)
void gemm_c2(const __bf16* __restrict__ W, const __bf16* __restrict__ B1,
             const __bf16* __restrict__ B2,
             __bf16* __restrict__ C1, __bf16* __restrict__ C2,
             int K, int lda, int ldb, int ldc,
             long sAz, long sBz, long sCz,
             float a1, int acc1, float a2, int acc2)
{
    __shared__ __bf16 L0[BM * LDP], L1[BN * LDP], L2[BN * LDP];

    const int z = blockIdx.z;
    const long aOff = (long)z * sAz, bOff = (long)z * sBz, cOff = (long)z * sCz;
    const int m0 = blockIdx.y * BM, n0 = blockIdx.x * BN;
    const int tid = threadIdx.x, lane = tid & 63, wave = tid >> 6;
    const int wr = wave >> 1, wc = wave & 1, fr = lane & 15, fkb = lane >> 4;
    const int row = tid >> 1, half = (tid & 1) << 4;

    const __bf16* Ar  = W  + aOff + (long)(m0 + row) * lda + half;
    const __bf16* B1r = B1 + bOff + (long)(n0 + row) * ldb + half;
    const __bf16* B2r = B2 + bOff + (long)(n0 + row) * ldb + half;

    f32x4 ac1[4][4], ac2[4][4];
    #pragma unroll
    for (int i = 0; i < 4; ++i)
        #pragma unroll
        for (int j = 0; j < 4; ++j) { ac1[i][j] = (f32x4)0.f; ac2[i][j] = (f32x4)0.f; }

    bf16x8 rA0, rA1, r10, r11, r20, r21;
    auto load = [&](int k0) {
        rA0 = *(const bf16x8*)(Ar + k0);  rA1 = *(const bf16x8*)(Ar + k0 + 8);
        r10 = *(const bf16x8*)(B1r + k0); r11 = *(const bf16x8*)(B1r + k0 + 8);
        r20 = *(const bf16x8*)(B2r + k0); r21 = *(const bf16x8*)(B2r + k0 + 8);
    };
    load(0);

    for (int k0 = 0; k0 < K; k0 += BK) {
        *(bf16x8*)&L0[row * LDP + half] = rA0; *(bf16x8*)&L0[row * LDP + half + 8] = rA1;
        *(bf16x8*)&L1[row * LDP + half] = r10; *(bf16x8*)&L1[row * LDP + half + 8] = r11;
        *(bf16x8*)&L2[row * LDP + half] = r20; *(bf16x8*)&L2[row * LDP + half + 8] = r21;
        __syncthreads();
        if (k0 + BK < K) load(k0 + BK);

        bf16x8 fa[4], f1[4], f2[4];
        #pragma unroll
        for (int i = 0; i < 4; ++i)
            fa[i] = *(const bf16x8*)&L0[(wr * 64 + i * 16 + fr) * LDP + fkb * 8];
        #pragma unroll
        for (int j = 0; j < 4; ++j) {
            f1[j] = *(const bf16x8*)&L1[(wc * 64 + j * 16 + fr) * LDP + fkb * 8];
            f2[j] = *(const bf16x8*)&L2[(wc * 64 + j * 16 + fr) * LDP + fkb * 8];
        }
        #pragma unroll
        for (int i = 0; i < 4; ++i)
            #pragma unroll
            for (int j = 0; j < 4; ++j) {
                ac1[i][j] = __builtin_amdgcn_mfma_f32_16x16x32_bf16(fa[i], f1[j], ac1[i][j], 0, 0, 0);
                ac2[i][j] = __builtin_amdgcn_mfma_f32_16x16x32_bf16(fa[i], f2[j], ac2[i][j], 0, 0, 0);
            }
        __syncthreads();
    }

    const int crow0 = (lane >> 4) * 4;
    #pragma unroll
    for (int i = 0; i < 4; ++i)
        #pragma unroll
        for (int j = 0; j < 4; ++j)
            #pragma unroll
            for (int r = 0; r < 4; ++r) {
                const int gm = m0 + wr * 64 + i * 16 + crow0 + r;
                const int gn = n0 + wc * 64 + j * 16 + fr;
                const long idx = cOff + (long)gm * ldc + gn;
                float v1 = ac1[i][j][r] * a1;
                if (acc1) v1 += (float)C1[idx];
                C1[idx] = (__bf16)v1;
                float v2 = ac2[i][j][r] * a2;
                if (acc2) v2 += (float)C2[idx];
                C2[idx] = (__bf16)v2;
            }
}

// ======================= transposes / converters =======================
__global__ __launch_bounds__(256)
void transpose2d(const float* __restrict__ in, float* __restrict__ out, int R, int C)
{
    __shared__ float t[32][33];
    const int c0 = blockIdx.x * 32, r0 = blockIdx.y * 32;
    const int tx = threadIdx.x & 31, tg = threadIdx.x >> 5;
    #pragma unroll
    for (int rr = tg; rr < 32; rr += 8) {
        const int r = r0 + rr, c = c0 + tx;
        t[rr][tx] = (r < R && c < C) ? in[(long)r * C + c] : 0.f;
    }
    __syncthreads();
    #pragma unroll
    for (int cc = tg; cc < 32; cc += 8) {
        const int c = c0 + cc, r = r0 + tx;
        if (c < C && r < R) out[(long)c * R + r] = t[tx][cc];
    }
}

__global__ __launch_bounds__(256)
void t_f2b(const float* __restrict__ in, __bf16* __restrict__ out, int R, int C)
{
    __shared__ float t[32][33];
    const int c0 = blockIdx.x * 32, r0 = blockIdx.y * 32;
    const int tx = threadIdx.x & 31, tg = threadIdx.x >> 5;
    #pragma unroll
    for (int rr = tg; rr < 32; rr += 8) {
        const int r = r0 + rr, c = c0 + tx;
        t[rr][tx] = (r < R && c < C) ? in[(long)r * C + c] : 0.f;
    }
    __syncthreads();
    #pragma unroll
    for (int cc = tg; cc < 32; cc += 8) {
        const int c = c0 + cc, r = r0 + tx;
        if (c < C && r < R) out[(long)c * R + r] = (__bf16)t[tx][cc];
    }
}

__global__ __launch_bounds__(256)
void t_f2b2(const float* __restrict__ in, __bf16* __restrict__ outT,
            __bf16* __restrict__ outC, int R, int C)
{
    __shared__ float t[32][33];
    const int c0 = blockIdx.x * 32, r0 = blockIdx.y * 32;
    const int tx = threadIdx.x & 31, tg = threadIdx.x >> 5;
    #pragma unroll
    for (int rr = tg; rr < 32; rr += 8) {
        const int r = r0 + rr, c = c0 + tx;
        const float v = (r < R && c < C) ? in[(long)r * C + c] : 0.f;
        t[rr][tx] = v;
        if (r < R && c < C) outC[(long)r * C + c] = (__bf16)v;
    }
    __syncthreads();
    #pragma unroll
    for (int cc = tg; cc < 32; cc += 8) {
        const int c = c0 + cc, r = r0 + tx;
        if (c < C && r < R) outT[(long)c * R + r] = t[tx][cc];
    }
}

__global__ __launch_bounds__(256)
void f2b_copy(const float* __restrict__ in, __bf16* __restrict__ out, long n)
{
    const long i = (long)blockIdx.x * 256 + threadIdx.x;
    if (i < n) out[i] = (__bf16)in[i];
}

// f32 [Rsrc][Ks] (row stride sld) -> bf16 [Rdst][Kd], zero-padded rows/cols
__global__ __launch_bounds__(256)
void cvtb(const float* __restrict__ src, __bf16* __restrict__ out,
          int Rsrc, int Rdst, int Ks, int Kd, int sld)
{
    const long i = (long)blockIdx.x * 256 + threadIdx.x;
    if (i >= (long)Rdst * Kd) return;
    const int r = (int)(i / Kd), k = (int)(i % Kd);
    out[i] = (__bf16)((r < Rsrc && k < Ks) ? src[(long)r * sld + k] : 0.f);
}

// f32 [R][C] -> transposed+padded bf16 [C][Rd]
__global__ __launch_bounds__(256)
void t_f2bp(const float* __restrict__ in, __bf16* __restrict__ out, int R, int C, int Rd)
{
    __shared__ float t[32][33];
    const int c0 = blockIdx.x * 32, r0 = blockIdx.y * 32;
    const int tx = threadIdx.x & 31, tg = threadIdx.x >> 5;
    #pragma unroll
    for (int rr = tg; rr < 32; rr += 8) {
        const int r = r0 + rr, c = c0 + tx;
        t[rr][tx] = (r < R && c < C) ? in[(long)r * C + c] : 0.f;
    }
    __syncthreads();
    #pragma unroll
    for (int cc = tg; cc < 32; cc += 8) {
        const int c = c0 + cc, r = r0 + tx;
        if (c < C && r < Rd) out[(long)c * Rd + r] = (__bf16)t[tx][cc];
    }
}

__global__ __launch_bounds__(256)
void t_b(const __bf16* __restrict__ in, __bf16* __restrict__ out,
         int R, int C, long siZ, long soZ)
{
    __shared__ __bf16 t[32][34];
    const int z = blockIdx.z;
    const long iB = (long)z * siZ, oB = (long)z * soZ;
    const int c0 = blockIdx.x * 32, r0 = blockIdx.y * 32;
    const int tx = threadIdx.x & 31, tg = threadIdx.x >> 5;
    #pragma unroll
    for (int rr = tg; rr < 32; rr += 8) {
        const int r = r0 + rr, c = c0 + tx;
        t[rr][tx] = (r < R && c < C) ? in[iB + (long)r * C + c] : (__bf16)0.f;
    }
    __syncthreads();
    #pragma unroll
    for (int cc = tg; cc < 32; cc += 8) {
        const int c = c0 + cc, r = r0 + tx;
        if (c < C && r < R) out[oB + (long)c * R + r] = t[tx][cc];
    }
}

__global__ __launch_bounds__(256)
void rot3b(const __bf16* __restrict__ in, __bf16* __restrict__ out,
           int Ad, int Bd, int Cd, long sIn, long sOut)
{
    __shared__ __bf16 t[32][34];
    const int zz = blockIdx.z;
    const int b = zz % Bd, bat = zz / Bd;
    const long iB = (long)bat * sIn, oB = (long)bat * sOut;
    const int c0 = blockIdx.x * 32, a0 = blockIdx.y * 32;
    const int tx = threadIdx.x & 31, tg = threadIdx.x >> 5;
    #pragma unroll
    for (int aa = tg; aa < 32; aa += 8) {
        const int a = a0 + aa, c = c0 + tx;
        t[aa][tx] = (a < Ad && c < Cd) ? in[iB + ((long)a * Bd + b) * Cd + c] : (__bf16)0.f;
    }
    __syncthreads();
    #pragma unroll
    for (int cc = tg; cc < 32; cc += 8) {
        const int c = c0 + cc, a = a0 + tx;
        if (c < Cd && a < Ad) out[oB + ((long)c * Bd + b) * Ad + a] = t[tx][cc];
    }
}

// ======================= table builders =======================
__global__ __launch_bounds__(256)
void make_dft_pair(__bf16* WfH, __bf16* WfL, __bf16* WiH, __bf16* WiL)
{
    const int i = blockIdx.x * 256 + threadIdx.x;
    const double w0 = 2.0 * 3.14159265358979323846 / 256.0;
    {
        const int n = i & 255, r = i >> 8, m = r & 127;
        const double th = (double)((m * n) & 255) * w0;
        const float v = (r < 128) ? (float)cos(th) : (float)-sin(th);
        __bf16 h, l; cvt_hl(v, h, l); WfH[i] = h; WfL[i] = l;
    }
    {
        const int k = i & 255, nn = i >> 8, m = k & 127;
        const double th = (double)((m * nn) & 255) * w0;
        const float sc = (m == 0 ? 1.0f : 2.0f) / 256.0f;
        const float v = (k < 128) ? sc * (float)cos(th) : -sc * (float)sin(th);
        __bf16 h, l; cvt_hl(v, h, l); WiH[i] = h; WiL[i] = l;
    }
}

__global__ __launch_bounds__(256)
void make_P1_pair(const float* __restrict__ pct, const float* __restrict__ wq,
                  __bf16* __restrict__ PH, __bf16* __restrict__ PL)
{
    const long i = (long)blockIdx.x * 256 + threadIdx.x;
    const int y = (int)(i & 127);
    const int l = (int)((i >> 7) & 127);
    const int m = (int)(i >> 14);
    const float v = pct[((long)l * MM + m) * NLAT + y] * wq[y];
    __bf16 h, lo; cvt_hl(v, h, lo); PH[i] = h; PL[i] = lo;
}

__global__ __launch_bounds__(256)
void make_Q_pair(const float* __restrict__ pct, __bf16* __restrict__ QH, __bf16* __restrict__ QL)
{
    __shared__ float t[32][33];
    const int m = blockIdx.z;
    const int y0 = blockIdx.x * 32, l0 = blockIdx.y * 32;
    const int tx = threadIdx.x & 31, tg = threadIdx.x >> 5;
    #pragma unroll
    for (int ll = tg; ll < 32; ll += 8)
        t[ll][tx] = pct[((long)(l0 + ll) * MM + m) * NLAT + (y0 + tx)];
    __syncthreads();
    #pragma unroll
    for (int yy = tg; yy < 32; yy += 8) {
        const long idx = ((long)m * NLAT + (y0 + yy)) * MM + (l0 + tx);
        __bf16 h, l; cvt_hl(t[tx][yy], h, l);
        QH[idx] = h; QL[idx] = l;
    }
}

// bf[l][o] = b1[l][o] + sum_j W1[l][o][j] * skip_b[l][j]
__global__ void fold_bias(const float* __restrict__ w1, const float* __restrict__ b1,
                          const float* __restrict__ sb, float* __restrict__ bf)
{
    const int l = blockIdx.x, o = threadIdx.x;
    const float* W = w1 + (long)l * 131072 + (long)o * 256;
    const float* s = sb + l * 256;
    float acc = b1[l * 512 + o];
    for (int j = 0; j < 256; ++j) acc += W[j] * s[j];
    bf[l * 512 + o] = acc;
}

// ======================= host =======================
extern "C" void kernel_launch(void* const* d_in, const int* in_sizes, int n_in,
                              void* d_out, int out_size, void* d_ws, size_t ws_size,
                              hipStream_t stream)
{
    const float* x       = (const float*)d_in[0];
    const float* pct     = (const float*)d_in[1];
    const float* wq      = (const float*)d_in[2];
    const float* pos     = (const float*)d_in[3];
    const float* enc_w   = (const float*)d_in[4];
    const float* spec_re = (const float*)d_in[5];
    const float* spec_im = (const float*)d_in[6];
    const float* skip_w  = (const float*)d_in[7];
    const float* skip_b  = (const float*)d_in[8];
    const float* mlp_w1  = (const float*)d_in[9];
    const float* mlp_b1  = (const float*)d_in[10];
    const float* mlp_w2  = (const float*)d_in[11];
    const float* mlp_b2  = (const float*)d_in[12];
    const float* dec_w1  = (const float*)d_in[13];
    const float* dec_b1  = (const float*)d_in[14];
    const float* dec_w2  = (const float*)d_in[15];

    char* base = (char*)d_ws;
    size_t off = 0;
    auto alloc = [&](size_t bytes) -> char* {
        char* p = base + off; off += (bytes + 255) & ~(size_t)255; return p;
    };

    float* xT   = (float*)alloc(1179648UL * 4);
    float* hA   = (float*)alloc(8388608UL * 4);
    float* hB   = (float*)alloc(8388608UL * 4);
    float* S1   = (float*)alloc(8388608UL * 4);
    float* Wfus = (float*)alloc(4UL * 131072 * 4);
    float* bfus = (float*)alloc(4UL * 512 * 4);
    float* skT  = (float*)alloc(65536UL * 4);
    __bf16* WfH = (__bf16*)alloc(65536UL * 2);
    __bf16* WfL = (__bf16*)alloc(65536UL * 2);
    __bf16* WiH = (__bf16*)alloc(65536UL * 2);
    __bf16* WiL = (__bf16*)alloc(65536UL * 2);
    __bf16* P1H = (__bf16*)alloc(2097152UL * 2);
    __bf16* P1L = (__bf16*)alloc(2097152UL * 2);
    __bf16* QH  = (__bf16*)alloc(2097152UL * 2);
    __bf16* QL  = (__bf16*)alloc(2097152UL * 2);
    __bf16* hcB = (__bf16*)alloc(8388608UL * 2);
    __bf16* h16 = (__bf16*)alloc(8388608UL * 2);
    __bf16* u16 = (__bf16*)alloc(8388608UL * 2);
    __bf16* m16 = (__bf16*)alloc(16777216UL * 2);
    __bf16* x16 = (__bf16*)alloc((long)YN * 64 * 2);
    __bf16* SB1 = (__bf16*)alloc(8388608UL * 2);
    __bf16* SB2 = (__bf16*)alloc(8388608UL * 2);
    __bf16* WtR = (__bf16*)alloc(8388608UL * 2);
    __bf16* WtI = (__bf16*)alloc(8388608UL * 2);
    __bf16* w116 = (__bf16*)alloc(4UL * 131072 * 2);
    __bf16* wf16 = (__bf16*)alloc(4UL * 131072 * 2);
    __bf16* w216 = (__bf16*)alloc(4UL * 131072 * 2);
    __bf16* d1h16 = (__bf16*)alloc(131072UL * 2);
    __bf16* d1x16 = (__bf16*)alloc(32768UL * 2);
    __bf16* d216  = (__bf16*)alloc(65536UL * 2);   // 128 rows (padded from 6) x 512
    if (off > ws_size) return;

    float* posT = S1;

    // ---- tables & fused weights ----
    make_dft_pair<<<256, 256, 0, stream>>>(WfH, WfL, WiH, WiL);
    make_P1_pair<<<8192, 256, 0, stream>>>(pct, wq, P1H, P1L);
    make_Q_pair<<<dim3(4, 4, 128), 256, 0, stream>>>(pct, QH, QL);
    transpose2d<<<dim3(1024, 2), 256, 0, stream>>>(x, xT, 36, YN);
    t_f2bp<<<dim3(1024, 2), 256, 0, stream>>>(x, x16, 36, YN, 64);
    transpose2d<<<dim3(1024, 8), 256, 0, stream>>>(pos, posT, 256, YN);
    for (int l = 0; l < NLAYERS; ++l) {
        transpose2d<<<dim3(8, 8), 256, 0, stream>>>(skip_w + (long)l * 65536, skT, 256, 256);
        gemm_nt<<<dim3(2, 4), 256, 0, stream>>>(mlp_w1 + (long)l * 131072, skT,
            Wfus + (long)l * 131072, 512, 256, 256, 256, 256, 256,
            nullptr, 0, nullptr, 1.0f, 0, 0);
        cvtb<<<512, 256, 0, stream>>>(Wfus + (long)l * 131072, wf16 + (long)l * 131072,
                                      512, 512, 256, 256, 256);
    }
    fold_bias<<<4, 512, 0, stream>>>(mlp_w1, mlp_b1, skip_b, bfus);
    cvtb<<<2048, 256, 0, stream>>>(mlp_w1, w116, 2048, 2048, 256, 256, 256);
    cvtb<<<2048, 256, 0, stream>>>(mlp_w2, w216, 1024, 1024, 512, 512, 512);
    cvtb<<<512, 256, 0, stream>>>(dec_w1, d1h16, 512, 512, 256, 256, 292);
    cvtb<<<128, 256, 0, stream>>>(dec_w1 + 256, d1x16, 512, 512, 36, 64, 292);
    cvtb<<<256, 256, 0, stream>>>(dec_w2, d216, 6, 128, 512, 512, 512);

    // ---- encoder: hA[yn][c] = xT·enc^T + posT ----
    gemm_nt<<<dim3(2, 256), 256, 0, stream>>>(xT, enc_w, hA, YN, EMB, INCH,
        INCH, INCH, EMB, nullptr, 0, posT, 1.0f, 0, 0);

    float* hcur = hA;
    float* hnext = hB;

    for (int l = 0; l < NLAYERS; ++l) {
        t_f2b2<<<dim3(8, 1024), 256, 0, stream>>>(hcur, hcB, h16, YN, 256);
        gemm_sp<<<dim3(256, 2, 1), 256, 0, stream>>>(WfH, WfL, hcB, nullptr,
            256, YN, 256, 256, 256, YN, 0, 0, 0u, 0, nullptr, SB2, 1.0f, 0);
        gemm_sp<<<dim3(1, 2, 256), 256, 0, stream>>>(SB2, nullptr, P1H, P1L,
            256, 128, 128, 128, 128, 128, 32768, 16384, 127u, 32768, nullptr, SB1, 1.0f, 0);
        t_b<<<dim3(4, 1024, 2), 256, 0, stream>>>(SB1, SB2, 32768, 128, RB, RB);
        t_f2b<<<dim3(4, 2048), 256, 0, stream>>>(spec_re + (long)l * 8388608, WtR, 65536, 128);
        t_f2b<<<dim3(4, 2048), 256, 0, stream>>>(spec_im + (long)l * 8388608, WtI, 65536, 128);
        gemm_c2<<<dim3(1, 2, 128), 256, 0, stream>>>(WtR, SB2, SB2 + RB, SB1, SB1 + RB,
            256, 256, 256, 128, 65536, 32768, 32768, 1.0f, 0, 1.0f, 0);
        gemm_c2<<<dim3(1, 2, 128), 256, 0, stream>>>(WtI, SB2 + RB, SB2, SB1, SB1 + RB,
            256, 256, 256, 128, 65536, 32768, 32768, -1.0f, 1, 1.0f, 1);
        rot3b<<<dim3(4, 4, 512), 256, 0, stream>>>(SB1, SB2, 128, 256, 128, RB, RB);
        gemm_sp<<<dim3(1, 2, 256), 256, 0, stream>>>(SB2, nullptr, QH, QL,
            256, 128, 128, 128, 128, 128, 32768, 16384, 127u, 32768, nullptr, SB1, 1.0f, 1);
        t_b<<<dim3(1024, 8, 1), 256, 0, stream>>>(SB1, SB2, 256, YN, 0, 0);
        gemm_sp<<<dim3(2, 2, 128), 256, 0, stream>>>(WiH, WiL, SB2, nullptr,
            256, 256, 256, 256, YN, 256, 0, 256, 0xFFFFFFFFu, 65536, nullptr, u16, 1.0f, 0);
        // fused mlp1: m16 = relu(u16·W1^T + h16·Wfus^T + bfus)
        gemm_bb<<<dim3(4, 256), 256, 0, stream>>>(u16, w116 + (long)l * 131072,
            256, 256, 256, h16, wf16 + (long)l * 131072, 256, 256, 256,
            nullptr, m16, YN, HID, HID, bfus + (long)l * 512, nullptr, 1);
        // mlp2: hnext = m16·W2^T + b2 + hcur
        gemm_bb<<<dim3(2, 256), 256, 0, stream>>>(m16, w216 + (long)l * 131072,
            512, 512, 512, nullptr, nullptr, 0, 0, 0,
            hnext, nullptr, YN, EMB, EMB, mlp_b2 + (long)l * EMB, hcur, 0);
        float* t = hcur; hcur = hnext; hnext = t;
    }

    // ---- decoder ----
    f2b_copy<<<32768, 256, 0, stream>>>(hcur, h16, 8388608);
    gemm_bb<<<dim3(4, 256), 256, 0, stream>>>(h16, d1h16, 256, 256, 256,
        x16, d1x16, 64, 64, 64,
        nullptr, m16, YN, HID, HID, dec_b1, nullptr, 1);
    gemm_bb<<<dim3(1, 256), 256, 0, stream>>>(m16, d216, 512, 512, 512,
        nullptr, nullptr, 0, 0, 0,
        S1, nullptr, YN, OUTCH, OUTCH, nullptr, nullptr, 0);
    transpose2d<<<dim3(1, 1024), 256, 0, stream>>>(S1, (float*)d_out, YN, OUTCH);

    (void)in_sizes; (void)n_in; (void)out_size;
}

// Round 20
// 1653.638 us; speedup vs baseline: 1.0641x; 1.0641x over previous
//
#include <hip/hip_runtime.h>
#include <hip/hip_bf16.h>
#include <math.h>

static constexpr int NLAT = 128, NLON = 256, MM = 128;
static constexpr int EMB = 256, INCH = 36, OUTCH = 6, HID = 512, NLAYERS = 4;
static constexpr int YN = 32768;
static constexpr long RB = 4194304;

using bf16x8 = __attribute__((ext_vector_type(8))) __bf16;
using f32x4  = __attribute__((ext_vector_type(4))) float;

static constexpr int BM = 128, BN = 128, BK = 32, LDP = 40;
static constexpr int BK2 = 64, LDP2 = 72;

__device__ __forceinline__ void cvt_hl(float v, __bf16& h, __bf16& l)
{
    h = (__bf16)v;
    l = (__bf16)(v - (float)h);
}
__device__ __forceinline__ void pack_hi_lo(const float* v, bf16x8& h0, bf16x8& h1,
                                           bf16x8& l0, bf16x8& l1)
{
    #pragma unroll
    for (int e = 0; e < 8; ++e) {
        const __bf16 h = (__bf16)v[e];
        h0[e] = h; l0[e] = (__bf16)(v[e] - (float)h);
        const __bf16 g = (__bf16)v[e + 8];
        h1[e] = g; l1[e] = (__bf16)(v[e + 8] - (float)g);
    }
}

// XCD-chunked block remap (bijective when nwg % 8 == 0): blocks with the same
// m-tile land consecutively on one XCD -> A-panel L2 locality.
__device__ __forceinline__ void xcd_remap2(int& bx, int& by)
{
    const uint gx = gridDim.x;
    const uint nwg = gx * gridDim.y;
    const uint lin = blockIdx.y * gx + blockIdx.x;
    const uint t = (lin & 7u) * (nwg >> 3) + (lin >> 3);
    by = (int)(t / gx);
    bx = (int)(t % gx);
}

// ======================= f32-input split NT GEMM (3-term, proven) =======================
__global__ __launch_bounds__(256)
void gemm_nt(const float* __restrict__ A, const float* __restrict__ B,
             float* __restrict__ C, int M, int N, int K,
             int lda, int ldb, int ldc,
             const float* __restrict__ bias, int biasCol,
             const float* __restrict__ addsrc,
             float alpha, int accum, int relu)
{
    __shared__ __bf16 Ah[BM][LDP], Al[BM][LDP], Bh[BN][LDP], Bl[BN][LDP];

    const int m0 = blockIdx.y * BM, n0 = blockIdx.x * BN;
    const int tid = threadIdx.x, lane = tid & 63, wave = tid >> 6;
    const int wr = wave >> 1, wc = wave & 1;
    const int fr = lane & 15, fkb = lane >> 4;
    const int sr = tid >> 1, sh = (tid & 1) << 4;

    f32x4 acc[4][4];
    #pragma unroll
    for (int i = 0; i < 4; ++i)
        #pragma unroll
        for (int j = 0; j < 4; ++j) acc[i][j] = (f32x4)0.f;

    const int ga = m0 + sr, gb = n0 + sr;
    const float* Arow = A + (long)ga * lda + sh;
    const float* Brow = B + (long)gb * ldb + sh;

    bf16x8 sAh0, sAh1, sAl0, sAl1, sBh0, sBh1, sBl0, sBl1;

    auto loadA = [&](int k0) {
        float v[16];
        if (ga < M && (k0 + sh + 16) <= K) {
            #pragma unroll
            for (int q = 0; q < 4; ++q) {
                const float4 f = *(const float4*)(Arow + k0 + q * 4);
                v[q*4+0]=f.x; v[q*4+1]=f.y; v[q*4+2]=f.z; v[q*4+3]=f.w;
            }
        } else {
            #pragma unroll
            for (int e = 0; e < 16; ++e)
                v[e] = (ga < M && (k0 + sh + e) < K) ? Arow[k0 + e] : 0.f;
        }
        pack_hi_lo(v, sAh0, sAh1, sAl0, sAl1);
    };
    auto loadB = [&](int k0) {
        float v[16];
        if (gb < N && (k0 + sh + 16) <= K) {
            #pragma unroll
            for (int q = 0; q < 4; ++q) {
                const float4 f = *(const float4*)(Brow + k0 + q * 4);
                v[q*4+0]=f.x; v[q*4+1]=f.y; v[q*4+2]=f.z; v[q*4+3]=f.w;
            }
        } else {
            #pragma unroll
            for (int e = 0; e < 16; ++e)
                v[e] = (gb < N && (k0 + sh + e) < K) ? Brow[k0 + e] : 0.f;
        }
        pack_hi_lo(v, sBh0, sBh1, sBl0, sBl1);
    };

    loadA(0); loadB(0);

    for (int k0 = 0; k0 < K; k0 += BK) {
        *(bf16x8*)&Ah[sr][sh]     = sAh0;  *(bf16x8*)&Ah[sr][sh + 8] = sAh1;
        *(bf16x8*)&Al[sr][sh]     = sAl0;  *(bf16x8*)&Al[sr][sh + 8] = sAl1;
        *(bf16x8*)&Bh[sr][sh]     = sBh0;  *(bf16x8*)&Bh[sr][sh + 8] = sBh1;
        *(bf16x8*)&Bl[sr][sh]     = sBl0;  *(bf16x8*)&Bl[sr][sh + 8] = sBl1;
        __syncthreads();

        if (k0 + BK < K) { loadA(k0 + BK); loadB(k0 + BK); }

        bf16x8 fah[4], fal[4], fbh[4], fbl[4];
        #pragma unroll
        for (int i = 0; i < 4; ++i) {
            const int r = wr * 64 + i * 16 + fr;
            fah[i] = *(const bf16x8*)&Ah[r][fkb * 8];
            fal[i] = *(const bf16x8*)&Al[r][fkb * 8];
        }
        #pragma unroll
        for (int j = 0; j < 4; ++j) {
            const int c = wc * 64 + j * 16 + fr;
            fbh[j] = *(const bf16x8*)&Bh[c][fkb * 8];
            fbl[j] = *(const bf16x8*)&Bl[c][fkb * 8];
        }
        #pragma unroll
        for (int i = 0; i < 4; ++i)
            #pragma unroll
            for (int j = 0; j < 4; ++j) {
                acc[i][j] = __builtin_amdgcn_mfma_f32_16x16x32_bf16(fah[i], fbh[j], acc[i][j], 0, 0, 0);
                acc[i][j] = __builtin_amdgcn_mfma_f32_16x16x32_bf16(fah[i], fbl[j], acc[i][j], 0, 0, 0);
                acc[i][j] = __builtin_amdgcn_mfma_f32_16x16x32_bf16(fal[i], fbh[j], acc[i][j], 0, 0, 0);
            }
        __syncthreads();
    }

    const int crow0 = (lane >> 4) * 4;
    #pragma unroll
    for (int i = 0; i < 4; ++i)
        #pragma unroll
        for (int j = 0; j < 4; ++j)
            #pragma unroll
            for (int r = 0; r < 4; ++r) {
                const int gm = m0 + wr * 64 + i * 16 + crow0 + r;
                const int gn = n0 + wc * 64 + j * 16 + fr;
                if (gm < M && gn < N) {
                    const long idx = (long)gm * ldc + gn;
                    float v = acc[i][j][r] * alpha;
                    if (accum)  v += C[idx];
                    if (bias)   v += bias[biasCol ? gn : gm];
                    if (addsrc) v += addsrc[idx];
                    if (relu)   v = fmaxf(v, 0.f);
                    C[idx] = v;
                }
            }
}

// ======================= all-bf16 NT GEMM, 2-segment, BK=64 (round-18 proven) ==========
// C = A1·B1^T [+ A2·B2^T] (+bias[col]) (+addsrc f32) (relu) -> f32 and/or bf16 out.
__global__ __launch_bounds__(256)
void gemm_bb(const __bf16* __restrict__ A1, const __bf16* __restrict__ B1,
             int K1, int lda1, int ldb1,
             const __bf16* __restrict__ A2, const __bf16* __restrict__ B2,
             int K2, int lda2, int ldb2,
             float* __restrict__ Cf, __bf16* __restrict__ Cb,
             int M, int N, int ldc,
             const float* __restrict__ bias, const float* __restrict__ addsrc,
             int relu)
{
    __shared__ __bf16 Ab[128][LDP2], Bb[128][LDP2];

    int bx, by; xcd_remap2(bx, by);
    const int m0 = by * BM, n0 = bx * BN;
    const int tid = threadIdx.x, lane = tid & 63, wave = tid >> 6;
    const int wr = wave >> 1, wc = wave & 1;
    const int fr = lane & 15, fkb = lane >> 4;
    const int srow = tid >> 1, scol = (tid & 1) << 5;   // 0 or 32

    f32x4 acc[4][4];
    #pragma unroll
    for (int i = 0; i < 4; ++i)
        #pragma unroll
        for (int j = 0; j < 4; ++j) acc[i][j] = (f32x4)0.f;

    const int ga = m0 + srow, gb = n0 + srow;

    for (int seg = 0; seg < 2; ++seg) {
        const __bf16* Ax = seg ? A2 : A1;
        if (!Ax) break;
        const __bf16* Bx = seg ? B2 : B1;
        const int Ks = seg ? K2 : K1;
        const int la = seg ? lda2 : lda1;
        const int lb = seg ? ldb2 : ldb1;
        const __bf16* Arow = Ax + (long)ga * la + scol;
        const __bf16* Brow = Bx + (long)gb * lb + scol;

        bf16x8 ra[4], rb[4];
        auto loadA = [&](int k0) {
            if (ga < M && (k0 + scol + 32) <= Ks) {
                #pragma unroll
                for (int q = 0; q < 4; ++q) ra[q] = *(const bf16x8*)(Arow + k0 + q * 8);
            } else {
                #pragma unroll
                for (int q = 0; q < 4; ++q)
                    #pragma unroll
                    for (int e = 0; e < 8; ++e)
                        ra[q][e] = (ga < M && (k0 + scol + q * 8 + e) < Ks)
                                   ? Arow[k0 + q * 8 + e] : (__bf16)0.f;
            }
        };
        auto loadB = [&](int k0) {
            if (gb < N && (k0 + scol + 32) <= Ks) {
                #pragma unroll
                for (int q = 0; q < 4; ++q) rb[q] = *(const bf16x8*)(Brow + k0 + q * 8);
            } else {
                #pragma unroll
                for (int q = 0; q < 4; ++q)
                    #pragma unroll
                    for (int e = 0; e < 8; ++e)
                        rb[q][e] = (gb < N && (k0 + scol + q * 8 + e) < Ks)
                                   ? Brow[k0 + q * 8 + e] : (__bf16)0.f;
            }
        };

        loadA(0); loadB(0);

        for (int k0 = 0; k0 < Ks; k0 += BK2) {
            #pragma unroll
            for (int q = 0; q < 4; ++q) {
                *(bf16x8*)&Ab[srow][scol + q * 8] = ra[q];
                *(bf16x8*)&Bb[srow][scol + q * 8] = rb[q];
            }
            __syncthreads();

            if (k0 + BK2 < Ks) { loadA(k0 + BK2); loadB(k0 + BK2); }

            bf16x8 fa[4][2], fb[4][2];
            #pragma unroll
            for (int i = 0; i < 4; ++i) {
                const int r = wr * 64 + i * 16 + fr;
                fa[i][0] = *(const bf16x8*)&Ab[r][fkb * 8];
                fa[i][1] = *(const bf16x8*)&Ab[r][32 + fkb * 8];
            }
            #pragma unroll
            for (int j = 0; j < 4; ++j) {
                const int c = wc * 64 + j * 16 + fr;
                fb[j][0] = *(const bf16x8*)&Bb[c][fkb * 8];
                fb[j][1] = *(const bf16x8*)&Bb[c][32 + fkb * 8];
            }
            #pragma unroll
            for (int i = 0; i < 4; ++i)
                #pragma unroll
                for (int j = 0; j < 4; ++j) {
                    acc[i][j] = __builtin_amdgcn_mfma_f32_16x16x32_bf16(fa[i][0], fb[j][0], acc[i][j], 0, 0, 0);
                    acc[i][j] = __builtin_amdgcn_mfma_f32_16x16x32_bf16(fa[i][1], fb[j][1], acc[i][j], 0, 0, 0);
                }
            __syncthreads();
        }
    }

    const int crow0 = (lane >> 4) * 4;
    #pragma unroll
    for (int i = 0; i < 4; ++i)
        #pragma unroll
        for (int j = 0; j < 4; ++j)
            #pragma unroll
            for (int r = 0; r < 4; ++r) {
                const int gm = m0 + wr * 64 + i * 16 + crow0 + r;
                const int gn = n0 + wc * 64 + j * 16 + fr;
                if (gm < M && gn < N) {
                    const long idx = (long)gm * ldc + gn;
                    float v = acc[i][j][r];
                    if (bias)   v += bias[gn];
                    if (addsrc) v += addsrc[idx];
                    if (relu)   v = fmaxf(v, 0.f);
                    if (Cf) Cf[idx] = v;
                    if (Cb) Cb[idx] = (__bf16)v;
                }
            }
}

// ======================= bf16 spectral NT GEMM =======================
__global__ __launch_bounds__(256)
void gemm_sp(const __bf16* __restrict__ Ah, const __bf16* __restrict__ Al,
             const __bf16* __restrict__ Bh, const __bf16* __restrict__ Bl,
             int M, int N, int K, int lda, int ldb, int ldc,
             long sAz, long sBz, unsigned zmaskB, long sCz,
             float* __restrict__ outF, __bf16* __restrict__ outB,
             float alpha, int kfromz)
{
    __shared__ __bf16 L0[BM * LDP], L1[BN * LDP], L2[BM * LDP];

    const int z = blockIdx.z;
    const long aOff = (long)z * sAz, bOff = (long)(z & zmaskB) * sBz, cOff = (long)z * sCz;
    const int m0 = blockIdx.y * BM, n0 = blockIdx.x * BN;
    const int tid = threadIdx.x, lane = tid & 63, wave = tid >> 6;
    const int wr = wave >> 1, wc = wave & 1, fr = lane & 15, fkb = lane >> 4;
    const int row = tid >> 1, half = (tid & 1) << 4;
    const int kst = kfromz ? (((z & 127) >> 5) << 5) : 0;
    const bool asp = (Al != nullptr), bsp = (Bl != nullptr);

    const __bf16* Ar = Ah + aOff + (long)(m0 + row) * lda + half;
    const __bf16* Br = Bh + bOff + (long)(n0 + row) * ldb + half;
    const __bf16* Xr = asp ? (Al + aOff + (long)(m0 + row) * lda + half)
                     : (bsp ? (Bl + bOff + (long)(n0 + row) * ldb + half) : nullptr);

    f32x4 acc[4][4];
    #pragma unroll
    for (int i = 0; i < 4; ++i)
        #pragma unroll
        for (int j = 0; j < 4; ++j) acc[i][j] = (f32x4)0.f;

    bf16x8 rA0, rA1, rB0, rB1, rX0, rX1;
    auto load = [&](int k0) {
        rA0 = *(const bf16x8*)(Ar + k0); rA1 = *(const bf16x8*)(Ar + k0 + 8);
        rB0 = *(const bf16x8*)(Br + k0); rB1 = *(const bf16x8*)(Br + k0 + 8);
        if (Xr) { rX0 = *(const bf16x8*)(Xr + k0); rX1 = *(const bf16x8*)(Xr + k0 + 8); }
    };
    load(kst);

    for (int k0 = kst; k0 < K; k0 += BK) {
        *(bf16x8*)&L0[row * LDP + half] = rA0; *(bf16x8*)&L0[row * LDP + half + 8] = rA1;
        *(bf16x8*)&L1[row * LDP + half] = rB0; *(bf16x8*)&L1[row * LDP + half + 8] = rB1;
        if (Xr) { *(bf16x8*)&L2[row * LDP + half] = rX0; *(bf16x8*)&L2[row * LDP + half + 8] = rX1; }
        __syncthreads();
        if (k0 + BK < K) load(k0 + BK);

        bf16x8 fa[4], fb[4], fx[4];
        #pragma unroll
        for (int i = 0; i < 4; ++i)
            fa[i] = *(const bf16x8*)&L0[(wr * 64 + i * 16 + fr) * LDP + fkb * 8];
        #pragma unroll
        for (int j = 0; j < 4; ++j)
            fb[j] = *(const bf16x8*)&L1[(wc * 64 + j * 16 + fr) * LDP + fkb * 8];
        if (asp) {
            #pragma unroll
            for (int i = 0; i < 4; ++i)
                fx[i] = *(const bf16x8*)&L2[(wr * 64 + i * 16 + fr) * LDP + fkb * 8];
        } else if (bsp) {
            #pragma unroll
            for (int j = 0; j < 4; ++j)
                fx[j] = *(const bf16x8*)&L2[(wc * 64 + j * 16 + fr) * LDP + fkb * 8];
        }
        #pragma unroll
        for (int i = 0; i < 4; ++i)
            #pragma unroll
            for (int j = 0; j < 4; ++j) {
                acc[i][j] = __builtin_amdgcn_mfma_f32_16x16x32_bf16(fa[i], fb[j], acc[i][j], 0, 0, 0);
                if (asp) acc[i][j] = __builtin_amdgcn_mfma_f32_16x16x32_bf16(fx[i], fb[j], acc[i][j], 0, 0, 0);
                else if (bsp) acc[i][j] = __builtin_amdgcn_mfma_f32_16x16x32_bf16(fa[i], fx[j], acc[i][j], 0, 0, 0);
            }
        __syncthreads();
    }

    const int crow0 = (lane >> 4) * 4;
    #pragma unroll
    for (int i = 0; i < 4; ++i)
        #pragma unroll
        for (int j = 0; j < 4; ++j)
            #pragma unroll
            for (int r = 0; r < 4; ++r) {
                const int gm = m0 + wr * 64 + i * 16 + crow0 + r;
                const int gn = n0 + wc * 64 + j * 16 + fr;
                const long idx = cOff + (long)gm * ldc + gn;
                const float v = acc[i][j][r] * alpha;
                if (outF) outF[idx] = v;
                if (outB) outB[idx] = (__bf16)v;
            }
}

// ======================= fused dual spec GEMM =======================
__global__ __launch_bounds__(256)
void gemm_c2(const __bf16* __restrict__ W, const __bf16* __restrict__ B1,
             const __bf16* __restrict__ B2,
             __bf16* __restrict__ C1, __bf16* __restrict__ C2,
             int K, int lda, int ldb, int ldc,
             long sAz, long sBz, long sCz,
             float a1, int acc1, float a2, int acc2)
{
    __shared__ __bf16 L0[BM * LDP], L1[BN * LDP], L2[BN * LDP];

    const int z = blockIdx.z;
    const long aOff = (long)z * sAz, bOff = (long)z * sBz, cOff = (long)z * sCz;
    const int m0 = blockIdx.y * BM, n0 = blockIdx.x * BN;
    const int tid = threadIdx.x, lane = tid & 63, wave = tid >> 6;
    const int wr = wave >> 1, wc = wave & 1, fr = lane & 15, fkb = lane >> 4;
    const int row = tid >> 1, half = (tid & 1) << 4;

    const __bf16* Ar  = W  + aOff + (long)(m0 + row) * lda + half;
    const __bf16* B1r = B1 + bOff + (long)(n0 + row) * ldb + half;
    const __bf16* B2r = B2 + bOff + (long)(n0 + row) * ldb + half;

    f32x4 ac1[4][4], ac2[4][4];
    #pragma unroll
    for (int i = 0; i < 4; ++i)
        #pragma unroll
        for (int j = 0; j < 4; ++j) { ac1[i][j] = (f32x4)0.f; ac2[i][j] = (f32x4)0.f; }

    bf16x8 rA0, rA1, r10, r11, r20, r21;
    auto load = [&](int k0) {
        rA0 = *(const bf16x8*)(Ar + k0);  rA1 = *(const bf16x8*)(Ar + k0 + 8);
        r10 = *(const bf16x8*)(B1r + k0); r11 = *(const bf16x8*)(B1r + k0 + 8);
        r20 = *(const bf16x8*)(B2r + k0); r21 = *(const bf16x8*)(B2r + k0 + 8);
    };
    load(0);

    for (int k0 = 0; k0 < K; k0 += BK) {
        *(bf16x8*)&L0[row * LDP + half] = rA0; *(bf16x8*)&L0[row * LDP + half + 8] = rA1;
        *(bf16x8*)&L1[row * LDP + half] = r10; *(bf16x8*)&L1[row * LDP + half + 8] = r11;
        *(bf16x8*)&L2[row * LDP + half] = r20; *(bf16x8*)&L2[row * LDP + half + 8] = r21;
        __syncthreads();
        if (k0 + BK < K) load(k0 + BK);

        bf16x8 fa[4], f1[4], f2[4];
        #pragma unroll
        for (int i = 0; i < 4; ++i)
            fa[i] = *(const bf16x8*)&L0[(wr * 64 + i * 16 + fr) * LDP + fkb * 8];
        #pragma unroll
        for (int j = 0; j < 4; ++j) {
            f1[j] = *(const bf16x8*)&L1[(wc * 64 + j * 16 + fr) * LDP + fkb * 8];
            f2[j] = *(const bf16x8*)&L2[(wc * 64 + j * 16 + fr) * LDP + fkb * 8];
        }
        #pragma unroll
        for (int i = 0; i < 4; ++i)
            #pragma unroll
            for (int j = 0; j < 4; ++j) {
                ac1[i][j] = __builtin_amdgcn_mfma_f32_16x16x32_bf16(fa[i], f1[j], ac1[i][j], 0, 0, 0);
                ac2[i][j] = __builtin_amdgcn_mfma_f32_16x16x32_bf16(fa[i], f2[j], ac2[i][j], 0, 0, 0);
            }
        __syncthreads();
    }

    const int crow0 = (lane >> 4) * 4;
    #pragma unroll
    for (int i = 0; i < 4; ++i)
        #pragma unroll
        for (int j = 0; j < 4; ++j)
            #pragma unroll
            for (int r = 0; r < 4; ++r) {
                const int gm = m0 + wr * 64 + i * 16 + crow0 + r;
                const int gn = n0 + wc * 64 + j * 16 + fr;
                const long idx = cOff + (long)gm * ldc + gn;
                float v1 = ac1[i][j][r] * a1;
                if (acc1) v1 += (float)C1[idx];
                C1[idx] = (__bf16)v1;
                float v2 = ac2[i][j][r] * a2;
                if (acc2) v2 += (float)C2[idx];
                C2[idx] = (__bf16)v2;
            }
}

// ======================= transposes / converters =======================
__global__ __launch_bounds__(256)
void transpose2d(const float* __restrict__ in, float* __restrict__ out, int R, int C)
{
    __shared__ float t[32][33];
    const int c0 = blockIdx.x * 32, r0 = blockIdx.y * 32;
    const int tx = threadIdx.x & 31, tg = threadIdx.x >> 5;
    #pragma unroll
    for (int rr = tg; rr < 32; rr += 8) {
        const int r = r0 + rr, c = c0 + tx;
        t[rr][tx] = (r < R && c < C) ? in[(long)r * C + c] : 0.f;
    }
    __syncthreads();
    #pragma unroll
    for (int cc = tg; cc < 32; cc += 8) {
        const int c = c0 + cc, r = r0 + tx;
        if (c < C && r < R) out[(long)c * R + r] = t[tx][cc];
    }
}

__global__ __launch_bounds__(256)
void t_f2b(const float* __restrict__ in, __bf16* __restrict__ out, int R, int C)
{
    __shared__ float t[32][33];
    const int c0 = blockIdx.x * 32, r0 = blockIdx.y * 32;
    const int tx = threadIdx.x & 31, tg = threadIdx.x >> 5;
    #pragma unroll
    for (int rr = tg; rr < 32; rr += 8) {
        const int r = r0 + rr, c = c0 + tx;
        t[rr][tx] = (r < R && c < C) ? in[(long)r * C + c] : 0.f;
    }
    __syncthreads();
    #pragma unroll
    for (int cc = tg; cc < 32; cc += 8) {
        const int c = c0 + cc, r = r0 + tx;
        if (c < C && r < R) out[(long)c * R + r] = (__bf16)t[tx][cc];
    }
}

__global__ __launch_bounds__(256)
void t_f2b2(const float* __restrict__ in, __bf16* __restrict__ outT,
            __bf16* __restrict__ outC, int R, int C)
{
    __shared__ float t[32][33];
    const int c0 = blockIdx.x * 32, r0 = blockIdx.y * 32;
    const int tx = threadIdx.x & 31, tg = threadIdx.x >> 5;
    #pragma unroll
    for (int rr = tg; rr < 32; rr += 8) {
        const int r = r0 + rr, c = c0 + tx;
        const float v = (r < R && c < C) ? in[(long)r * C + c] : 0.f;
        t[rr][tx] = v;
        if (r < R && c < C) outC[(long)r * C + c] = (__bf16)v;
    }
    __syncthreads();
    #pragma unroll
    for (int cc = tg; cc < 32; cc += 8) {
        const int c = c0 + cc, r = r0 + tx;
        if (c < C && r < R) outT[(long)c * R + r] = t[tx][cc];
    }
}

// f32 [Rsrc][Ks] (row stride sld) -> bf16 [Rdst][Kd], zero-padded rows/cols
__global__ __launch_bounds__(256)
void cvtb(const float* __restrict__ src, __bf16* __restrict__ out,
          int Rsrc, int Rdst, int Ks, int Kd, int sld)
{
    const long i = (long)blockIdx.x * 256 + threadIdx.x;
    if (i >= (long)Rdst * Kd) return;
    const int r = (int)(i / Kd), k = (int)(i % Kd);
    out[i] = (__bf16)((r < Rsrc && k < Ks) ? src[(long)r * sld + k] : 0.f);
}

// f32 [R][C] -> transposed+padded bf16 [C][Rd]
__global__ __launch_bounds__(256)
void t_f2bp(const float* __restrict__ in, __bf16* __restrict__ out, int R, int C, int Rd)
{
    __shared__ float t[32][33];
    const int c0 = blockIdx.x * 32, r0 = blockIdx.y * 32;
    const int tx = threadIdx.x & 31, tg = threadIdx.x >> 5;
    #pragma unroll
    for (int rr = tg; rr < 32; rr += 8) {
        const int r = r0 + rr, c = c0 + tx;
        t[rr][tx] = (r < R && c < C) ? in[(long)r * C + c] : 0.f;
    }
    __syncthreads();
    #pragma unroll
    for (int cc = tg; cc < 32; cc += 8) {
        const int c = c0 + cc, r = r0 + tx;
        if (c < C && r < Rd) out[(long)c * Rd + r] = (__bf16)t[tx][cc];
    }
}

__global__ __launch_bounds__(256)
void t_b(const __bf16* __restrict__ in, __bf16* __restrict__ out,
         int R, int C, long siZ, long soZ)
{
    __shared__ __bf16 t[32][34];
    const int z = blockIdx.z;
    const long iB = (long)z * siZ, oB = (long)z * soZ;
    const int c0 = blockIdx.x * 32, r0 = blockIdx.y * 32;
    const int tx = threadIdx.x & 31, tg = threadIdx.x >> 5;
    #pragma unroll
    for (int rr = tg; rr < 32; rr += 8) {
        const int r = r0 + rr, c = c0 + tx;
        t[rr][tx] = (r < R && c < C) ? in[iB + (long)r * C + c] : (__bf16)0.f;
    }
    __syncthreads();
    #pragma unroll
    for (int cc = tg; cc < 32; cc += 8) {
        const int c = c0 + cc, r = r0 + tx;
        if (c < C && r < R) out[oB + (long)c * R + r] = t[tx][cc];
    }
}

__global__ __launch_bounds__(256)
void rot3b(const __bf16* __restrict__ in, __bf16* __restrict__ out,
           int Ad, int Bd, int Cd, long sIn, long sOut)
{
    __shared__ __bf16 t[32][34];
    const int zz = blockIdx.z;
    const int b = zz % Bd, bat = zz / Bd;
    const long iB = (long)bat * sIn, oB = (long)bat * sOut;
    const int c0 = blockIdx.x * 32, a0 = blockIdx.y * 32;
    const int tx = threadIdx.x & 31, tg = threadIdx.x >> 5;
    #pragma unroll
    for (int aa = tg; aa < 32; aa += 8) {
        const int a = a0 + aa, c = c0 + tx;
        t[aa][tx] = (a < Ad && c < Cd) ? in[iB + ((long)a * Bd + b) * Cd + c] : (__bf16)0.f;
    }
    __syncthreads();
    #pragma unroll
    for (int cc = tg; cc < 32; cc += 8) {
        const int c = c0 + cc, a = a0 + tx;
        if (c < Cd && a < Ad) out[oB + ((long)c * Bd + b) * Ad + a] = t[tx][cc];
    }
}

// ======================= table builders =======================
__global__ __launch_bounds__(256)
void make_dft_pair(__bf16* WfH, __bf16* WfL, __bf16* WiH, __bf16* WiL)
{
    const int i = blockIdx.x * 256 + threadIdx.x;
    const double w0 = 2.0 * 3.14159265358979323846 / 256.0;
    {
        const int n = i & 255, r = i >> 8, m = r & 127;
        const double th = (double)((m * n) & 255) * w0;
        const float v = (r < 128) ? (float)cos(th) : (float)-sin(th);
        __bf16 h, l; cvt_hl(v, h, l); WfH[i] = h; WfL[i] = l;
    }
    {
        const int k = i & 255, nn = i >> 8, m = k & 127;
        const double th = (double)((m * nn) & 255) * w0;
        const float sc = (m == 0 ? 1.0f : 2.0f) / 256.0f;
        const float v = (k < 128) ? sc * (float)cos(th) : -sc * (float)sin(th);
        __bf16 h, l; cvt_hl(v, h, l); WiH[i] = h; WiL[i] = l;
    }
}

__global__ __launch_bounds__(256)
void make_P1_pair(const float* __restrict__ pct, const float* __restrict__ wq,
                  __bf16* __restrict__ PH, __bf16* __restrict__ PL)
{
    const long i = (long)blockIdx.x * 256 + threadIdx.x;
    const int y = (int)(i & 127);
    const int l = (int)((i >> 7) & 127);
    const int m = (int)(i >> 14);
    const float v = pct[((long)l * MM + m) * NLAT + y] * wq[y];
    __bf16 h, lo; cvt_hl(v, h, lo); PH[i] = h; PL[i] = lo;
}

__global__ __launch_bounds__(256)
void make_Q_pair(const float* __restrict__ pct, __bf16* __restrict__ QH, __bf16* __restrict__ QL)
{
    __shared__ float t[32][33];
    const int m = blockIdx.z;
    const int y0 = blockIdx.x * 32, l0 = blockIdx.y * 32;
    const int tx = threadIdx.x & 31, tg = threadIdx.x >> 5;
    #pragma unroll
    for (int ll = tg; ll < 32; ll += 8)
        t[ll][tx] = pct[((long)(l0 + ll) * MM + m) * NLAT + (y0 + tx)];
    __syncthreads();
    #pragma unroll
    for (int yy = tg; yy < 32; yy += 8) {
        const long idx = ((long)m * NLAT + (y0 + yy)) * MM + (l0 + tx);
        __bf16 h, l; cvt_hl(t[tx][yy], h, l);
        QH[idx] = h; QL[idx] = l;
    }
}

// bf[l][o] = b1[l][o] + sum_j W1[l][o][j] * skip_b[l][j]
__global__ void fold_bias(const float* __restrict__ w1, const float* __restrict__ b1,
                          const float* __restrict__ sb, float* __restrict__ bf)
{
    const int l = blockIdx.x, o = threadIdx.x;
    const float* W = w1 + (long)l * 131072 + (long)o * 256;
    const float* s = sb + l * 256;
    float acc = b1[l * 512 + o];
    for (int j = 0; j < 256; ++j) acc += W[j] * s[j];
    bf[l * 512 + o] = acc;
}

// ======================= host =======================
extern "C" void kernel_launch(void* const* d_in, const int* in_sizes, int n_in,
                              void* d_out, int out_size, void* d_ws, size_t ws_size,
                              hipStream_t stream)
{
    const float* x       = (const float*)d_in[0];
    const float* pct     = (const float*)d_in[1];
    const float* wq      = (const float*)d_in[2];
    const float* pos     = (const float*)d_in[3];
    const float* enc_w   = (const float*)d_in[4];
    const float* spec_re = (const float*)d_in[5];
    const float* spec_im = (const float*)d_in[6];
    const float* skip_w  = (const float*)d_in[7];
    const float* skip_b  = (const float*)d_in[8];
    const float* mlp_w1  = (const float*)d_in[9];
    const float* mlp_b1  = (const float*)d_in[10];
    const float* mlp_w2  = (const float*)d_in[11];
    const float* mlp_b2  = (const float*)d_in[12];
    const float* dec_w1  = (const float*)d_in[13];
    const float* dec_b1  = (const float*)d_in[14];
    const float* dec_w2  = (const float*)d_in[15];

    char* base = (char*)d_ws;
    size_t off = 0;
    auto alloc = [&](size_t bytes) -> char* {
        char* p = base + off; off += (bytes + 255) & ~(size_t)255; return p;
    };

    float* xT   = (float*)alloc(1179648UL * 4);
    float* hA   = (float*)alloc(8388608UL * 4);
    float* hB   = (float*)alloc(8388608UL * 4);
    float* S1   = (float*)alloc(8388608UL * 4);
    float* Wfus = (float*)alloc(4UL * 131072 * 4);
    float* bfus = (float*)alloc(4UL * 512 * 4);
    float* skT  = (float*)alloc(65536UL * 4);
    __bf16* WfH = (__bf16*)alloc(65536UL * 2);
    __bf16* WfL = (__bf16*)alloc(65536UL * 2);
    __bf16* WiH = (__bf16*)alloc(65536UL * 2);
    __bf16* WiL = (__bf16*)alloc(65536UL * 2);
    __bf16* P1H = (__bf16*)alloc(2097152UL * 2);
    __bf16* P1L = (__bf16*)alloc(2097152UL * 2);
    __bf16* QH  = (__bf16*)alloc(2097152UL * 2);
    __bf16* QL  = (__bf16*)alloc(2097152UL * 2);
    __bf16* hcB = (__bf16*)alloc(8388608UL * 2);
    __bf16* h16 = (__bf16*)alloc(8388608UL * 2);
    __bf16* u16 = (__bf16*)alloc(8388608UL * 2);
    __bf16* m16 = (__bf16*)alloc(16777216UL * 2);
    __bf16* x16 = (__bf16*)alloc((long)YN * 64 * 2);
    __bf16* SB1 = (__bf16*)alloc(8388608UL * 2);
    __bf16* SB2 = (__bf16*)alloc(8388608UL * 2);
    __bf16* WtR = (__bf16*)alloc(8388608UL * 2);
    __bf16* WtI = (__bf16*)alloc(8388608UL * 2);
    __bf16* w116 = (__bf16*)alloc(4UL * 131072 * 2);
    __bf16* wf16 = (__bf16*)alloc(4UL * 131072 * 2);
    __bf16* w216 = (__bf16*)alloc(4UL * 131072 * 2);
    __bf16* d1h16 = (__bf16*)alloc(131072UL * 2);
    __bf16* d1x16 = (__bf16*)alloc(32768UL * 2);
    __bf16* d216  = (__bf16*)alloc(65536UL * 2);   // 128 rows (padded from 6) x 512
    if (off > ws_size) return;

    float* posT = S1;

    // ---- tables & fused weights ----
    make_dft_pair<<<256, 256, 0, stream>>>(WfH, WfL, WiH, WiL);
    make_P1_pair<<<8192, 256, 0, stream>>>(pct, wq, P1H, P1L);
    make_Q_pair<<<dim3(4, 4, 128), 256, 0, stream>>>(pct, QH, QL);
    transpose2d<<<dim3(1024, 2), 256, 0, stream>>>(x, xT, 36, YN);
    t_f2bp<<<dim3(1024, 2), 256, 0, stream>>>(x, x16, 36, YN, 64);
    transpose2d<<<dim3(1024, 8), 256, 0, stream>>>(pos, posT, 256, YN);
    for (int l = 0; l < NLAYERS; ++l) {
        transpose2d<<<dim3(8, 8), 256, 0, stream>>>(skip_w + (long)l * 65536, skT, 256, 256);
        gemm_nt<<<dim3(2, 4), 256, 0, stream>>>(mlp_w1 + (long)l * 131072, skT,
            Wfus + (long)l * 131072, 512, 256, 256, 256, 256, 256,
            nullptr, 0, nullptr, 1.0f, 0, 0);
        cvtb<<<512, 256, 0, stream>>>(Wfus + (long)l * 131072, wf16 + (long)l * 131072,
                                      512, 512, 256, 256, 256);
    }
    fold_bias<<<4, 512, 0, stream>>>(mlp_w1, mlp_b1, skip_b, bfus);
    cvtb<<<2048, 256, 0, stream>>>(mlp_w1, w116, 2048, 2048, 256, 256, 256);
    cvtb<<<2048, 256, 0, stream>>>(mlp_w2, w216, 1024, 1024, 512, 512, 512);
    cvtb<<<512, 256, 0, stream>>>(dec_w1, d1h16, 512, 512, 256, 256, 292);
    cvtb<<<128, 256, 0, stream>>>(dec_w1 + 256, d1x16, 512, 512, 36, 64, 292);
    cvtb<<<256, 256, 0, stream>>>(dec_w2, d216, 6, 128, 512, 512, 512);

    // ---- encoder: hA[yn][c] = xT·enc^T + posT ----
    gemm_nt<<<dim3(2, 256), 256, 0, stream>>>(xT, enc_w, hA, YN, EMB, INCH,
        INCH, INCH, EMB, nullptr, 0, posT, 1.0f, 0, 0);

    float* hcur = hA;
    float* hnext = hB;

    for (int l = 0; l < NLAYERS; ++l) {
        t_f2b2<<<dim3(8, 1024), 256, 0, stream>>>(hcur, hcB, h16, YN, 256);
        gemm_sp<<<dim3(256, 2, 1), 256, 0, stream>>>(WfH, WfL, hcB, nullptr,
            256, YN, 256, 256, 256, YN, 0, 0, 0u, 0, nullptr, SB2, 1.0f, 0);
        gemm_sp<<<dim3(1, 2, 256), 256, 0, stream>>>(SB2, nullptr, P1H, P1L,
            256, 128, 128, 128, 128, 128, 32768, 16384, 127u, 32768, nullptr, SB1, 1.0f, 0);
        t_b<<<dim3(4, 1024, 2), 256, 0, stream>>>(SB1, SB2, 32768, 128, RB, RB);
        t_f2b<<<dim3(4, 2048), 256, 0, stream>>>(spec_re + (long)l * 8388608, WtR, 65536, 128);
        t_f2b<<<dim3(4, 2048), 256, 0, stream>>>(spec_im + (long)l * 8388608, WtI, 65536, 128);
        gemm_c2<<<dim3(1, 2, 128), 256, 0, stream>>>(WtR, SB2, SB2 + RB, SB1, SB1 + RB,
            256, 256, 256, 128, 65536, 32768, 32768, 1.0f, 0, 1.0f, 0);
        gemm_c2<<<dim3(1, 2, 128), 256, 0, stream>>>(WtI, SB2 + RB, SB2, SB1, SB1 + RB,
            256, 256, 256, 128, 65536, 32768, 32768, -1.0f, 1, 1.0f, 1);
        rot3b<<<dim3(4, 4, 512), 256, 0, stream>>>(SB1, SB2, 128, 256, 128, RB, RB);
        gemm_sp<<<dim3(1, 2, 256), 256, 0, stream>>>(SB2, nullptr, QH, QL,
            256, 128, 128, 128, 128, 128, 32768, 16384, 127u, 32768, nullptr, SB1, 1.0f, 1);
        t_b<<<dim3(1024, 8, 1), 256, 0, stream>>>(SB1, SB2, 256, YN, 0, 0);
        gemm_sp<<<dim3(2, 2, 128), 256, 0, stream>>>(WiH, WiL, SB2, nullptr,
            256, 256, 256, 256, YN, 256, 0, 256, 0xFFFFFFFFu, 65536, nullptr, u16, 1.0f, 0);
        // fused mlp1: m16 = relu(u16·W1^T + h16·Wfus^T + bfus)
        gemm_bb<<<dim3(4, 256), 256, 0, stream>>>(u16, w116 + (long)l * 131072,
            256, 256, 256, h16, wf16 + (long)l * 131072, 256, 256, 256,
            nullptr, m16, YN, HID, HID, bfus + (long)l * 512, nullptr, 1);
        // mlp2: hnext = m16·W2^T + b2 + hcur  (last layer also emits bf16 h16 for decoder)
        gemm_bb<<<dim3(2, 256), 256, 0, stream>>>(m16, w216 + (long)l * 131072,
            512, 512, 512, nullptr, nullptr, 0, 0, 0,
            hnext, (l == NLAYERS - 1) ? h16 : nullptr, YN, EMB, EMB,
            mlp_b2 + (long)l * EMB, hcur, 0);
        float* t = hcur; hcur = hnext; hnext = t;
    }

    // ---- decoder (h16 already produced by last mlp2) ----
    gemm_bb<<<dim3(4, 256), 256, 0, stream>>>(h16, d1h16, 256, 256, 256,
        x16, d1x16, 64, 64, 64,
        nullptr, m16, YN, HID, HID, dec_b1, nullptr, 1);
    gemm_bb<<<dim3(1, 256), 256, 0, stream>>>(m16, d216, 512, 512, 512,
        nullptr, nullptr, 0, 0, 0,
        S1, nullptr, YN, OUTCH, OUTCH, nullptr, nullptr, 0);
    transpose2d<<<dim3(1, 1024), 256, 0, stream>>>(S1, (float*)d_out, YN, OUTCH);

    (void)in_sizes; (void)n_in; (void)out_size;
}